// Round 5
// baseline (236.851 us; speedup 1.0000x reference)
//
#include <hip/hip_runtime.h>

// OHEM loss, specialized for NUM_CLASSES == 1:
//   ce = logsumexp(cls_preds, axis=2) - cls_preds[...,0] == 0 exactly,
//   so cls_loss == 0 and hard-negative mining is dead code.
//   out = 0.2 * sum_{pos} smooth_l1(loc_preds - loc_targets) / num_pos
//
// Round 4 (resubmit after 3x GPU acquisition timeout): kill the grid-stride
// loop (latency-bound at 2.8 TB/s effective). One thread = 2 anchors, 9
// independent loads issued back-to-back, branchless masked f32 compute,
// single block-reduce, exact-cover grid (no tail loop).

constexpr int BLK = 256;

__device__ __forceinline__ float sl1(float d) {
    float ax = fabsf(d);
    return (ax < 1.0f) ? 0.5f * d * d : ax - 0.5f;
}

__device__ __forceinline__ float sl1x8(const float4& p0, const float4& p1,
                                       const float4& q0, const float4& q1) {
    return sl1(p0.x - q0.x) + sl1(p0.y - q0.y) + sl1(p0.z - q0.z) + sl1(p0.w - q0.w)
         + sl1(p1.x - q1.x) + sl1(p1.y - q1.y) + sl1(p1.z - q1.z) + sl1(p1.w - q1.w);
}

__global__ __launch_bounds__(BLK) void ohem_partial(
        const float4* __restrict__ loc_p4,   // [n_anchor*2] float4
        const float4* __restrict__ loc_t4,   // [n_anchor*2] float4
        const int2*   __restrict__ cls_t2,   // [n_anchor/2] int2
        double* __restrict__ part_sum,
        int*    __restrict__ part_cnt,
        int n_pair)
{
    const int t = blockIdx.x * BLK + threadIdx.x;   // pair index (2 anchors)
    float s = 0.0f;
    int cnt = 0;
    if (t < n_pair) {
        const int2 c = cls_t2[t];
        const int b = t * 4;
        // 8 independent float4 loads + int2, one waitcnt, no loop, no drain cycle.
        float4 p0 = loc_p4[b + 0], p1 = loc_p4[b + 1], p2 = loc_p4[b + 2], p3 = loc_p4[b + 3];
        float4 q0 = loc_t4[b + 0], q1 = loc_t4[b + 1], q2 = loc_t4[b + 2], q3 = loc_t4[b + 3];
        const float s0 = sl1x8(p0, p1, q0, q1);
        const float s1 = sl1x8(p2, p3, q2, q3);
        const float m0 = (c.x > 0) ? 1.0f : 0.0f;
        const float m1 = (c.y > 0) ? 1.0f : 0.0f;
        s   = m0 * s0 + m1 * s1;          // branchless mask
        cnt = (c.x > 0) + (c.y > 0);
    }
    // wave-64 reduce (f64 from here on)
    double acc = (double)s;
    #pragma unroll
    for (int off = 32; off > 0; off >>= 1) {
        acc += __shfl_down(acc, off, 64);
        cnt += __shfl_down(cnt, off, 64);
    }
    __shared__ double ssum[BLK / 64];
    __shared__ int    scnt[BLK / 64];
    const int lane = threadIdx.x & 63;
    const int wid  = threadIdx.x >> 6;
    if (lane == 0) { ssum[wid] = acc; scnt[wid] = cnt; }
    __syncthreads();
    if (threadIdx.x == 0) {
        double a = 0.0; int c = 0;
        #pragma unroll
        for (int w = 0; w < BLK / 64; ++w) { a += ssum[w]; c += scnt[w]; }
        part_sum[blockIdx.x] = a;
        part_cnt[blockIdx.x] = c;
    }
}

__global__ __launch_bounds__(BLK) void ohem_final(
        const double* __restrict__ part_sum,
        const int*    __restrict__ part_cnt,
        float* __restrict__ out, int nblk)
{
    double acc = 0.0;
    long long cnt = 0;
    for (int i = threadIdx.x; i < nblk; i += BLK) {
        acc += part_sum[i];
        cnt += part_cnt[i];
    }
    #pragma unroll
    for (int off = 32; off > 0; off >>= 1) {
        acc += __shfl_down(acc, off, 64);
        cnt += __shfl_down(cnt, off, 64);
    }
    __shared__ double    ssum[BLK / 64];
    __shared__ long long scnt[BLK / 64];
    const int lane = threadIdx.x & 63;
    const int wid  = threadIdx.x >> 6;
    if (lane == 0) { ssum[wid] = acc; scnt[wid] = cnt; }
    __syncthreads();
    if (threadIdx.x == 0) {
        double a = 0.0; long long c = 0;
        #pragma unroll
        for (int w = 0; w < BLK / 64; ++w) { a += ssum[w]; c += scnt[w]; }
        out[0] = (float)(0.2 * a / (double)c);
    }
}

extern "C" void kernel_launch(void* const* d_in, const int* in_sizes, int n_in,
                              void* d_out, int out_size, void* d_ws, size_t ws_size,
                              hipStream_t stream) {
    const float4* loc_p4 = (const float4*)d_in[0];  // [B, A, 8] f32 -> float4 pairs
    const float4* loc_t4 = (const float4*)d_in[1];
    // d_in[2] (cls_preds) provably unused: ce == 0 when C == 1.
    const int2*   cls_t2 = (const int2*)d_in[3];    // [B, A] i32, read 2 at a time
    const int n_anchor = in_sizes[3];               // B * A = 3,200,000 (even)
    const int n_pair   = n_anchor / 2;              // 1,600,000
    const int nblk     = (n_pair + BLK - 1) / BLK;  // 6250, exact cover

    double* part_sum = (double*)d_ws;
    int*    part_cnt = (int*)((char*)d_ws + (size_t)nblk * sizeof(double));

    ohem_partial<<<nblk, BLK, 0, stream>>>(loc_p4, loc_t4, cls_t2,
                                           part_sum, part_cnt, n_pair);
    ohem_final<<<1, BLK, 0, stream>>>(part_sum, part_cnt, (float*)d_out, nblk);
}